// Round 1
// baseline (334.517 us; speedup 1.0000x reference)
//
#include <hip/hip_runtime.h>
#include <math.h>

#define CHN_ 256
#define EPS_ 1e-5f

// LDS row strides (floats) - chosen for 16B alignment + bank-conflict freedom
#define XFS  260   // xf tile [16][260]
#define WINS 33    // in_proj  [128][33] (b32 reads, (33d+dd)%32=(d+dd)%32 distinct)
#define WXPS 68    // x_proj   [34][68]
#define WOUTS 68   // out_proj [32][68]
#define U2S  68    // u2 / y   [128][68]
#define BCS  36    // xdbl rows: [0,1]=dt, [4..19]=B, [20..35]=C (16B-aligned)

__device__ __forceinline__ float sigmoidf_(float v) { return 1.f / (1.f + __expf(-v)); }

__global__ __launch_bounds__(1024) void spe_mamba_main(
    const float* __restrict__ x,
    const float* __restrict__ Win,    // (128,32)
    const float* __restrict__ convw,  // (64,1,4)
    const float* __restrict__ convb,  // (64,)
    const float* __restrict__ Wxp,    // (34,64)
    const float* __restrict__ dtw,    // (64,2)
    const float* __restrict__ dtb,    // (64,)
    const float* __restrict__ Alog,   // (64,16)
    const float* __restrict__ Dvec,   // (64,)
    const float* __restrict__ Wout,   // (32,64)
    float* __restrict__ pre,          // (B,256,64,64) pre-GN staging (= d_out)
    float* __restrict__ stats)        // ws: [B][4][2] sum/sumsq (atomic)
{
    __shared__ float xf_s[16 * XFS];      // also reused as out staging [p][m*8+t]
    __shared__ float Win_s[128 * WINS];
    __shared__ float Wxp_s[34 * WXPS];
    __shared__ float Wout_s[32 * WOUTS];
    __shared__ float u2_s[128 * U2S];     // u2, later y
    __shared__ float bc_s[128 * BCS];
    __shared__ float A_s[64 * 17];
    __shared__ float convw_s[64 * 5];
    __shared__ float convb_s[64];
    __shared__ float dtw_s[128];
    __shared__ float dtb_s[64];
    __shared__ float Dp_s[64];
    __shared__ float gred[8];             // [group][sum,sumsq]

    const int tid = threadIdx.x;
    const int bid = blockIdx.x;           // 1024 blocks, 16 px each
    const int b   = bid >> 8;             // 256 blocks per image
    const int hw0 = (bid & 255) << 4;     // pixel offset in 64x64 plane (16 consecutive w)

    // ---------------- phase 0: stage x tile + weights ----------------
    {
        const float* xb = x + ((b * CHN_) << 12) + hw0;
        const int pp = tid & 15, c0 = tid >> 4;
#pragma unroll
        for (int k = 0; k < 4; ++k) {
            const int c = c0 + (k << 6);
            xf_s[pp * XFS + c] = xb[(c << 12) + pp];
        }
        const int r5 = tid >> 5, c5 = tid & 31;
#pragma unroll
        for (int k = 0; k < 4; ++k) {
            const int r = r5 + (k << 5);
            Win_s[r * WINS + c5] = Win[(r << 5) + c5];
        }
        const int r6 = tid >> 6, c6 = tid & 63;
        Wxp_s[r6 * WXPS + c6] = Wxp[(r6 << 6) + c6];
        Wxp_s[(r6 + 16) * WXPS + c6] = Wxp[((r6 + 16) << 6) + c6];
        if (r6 < 2) Wxp_s[(r6 + 32) * WXPS + c6] = Wxp[((r6 + 32) << 6) + c6];
        Wout_s[r6 * WOUTS + c6] = Wout[(r6 << 6) + c6];
        Wout_s[(r6 + 16) * WOUTS + c6] = Wout[((r6 + 16) << 6) + c6];
        {
            const int rd = tid >> 4, s = tid & 15;
            A_s[rd * 17 + s] = -__expf(Alog[(rd << 4) + s]);  // A = -exp(A_log)
        }
        if (tid < 256) { const int dd = tid >> 2, kk = tid & 3; convw_s[dd * 5 + kk] = convw[(dd << 2) + kk]; }
        if (tid < 128) dtw_s[tid] = dtw[tid];
        if (tid < 64)  { convb_s[tid] = convb[tid]; dtb_s[tid] = dtb[tid]; Dp_s[tid] = Dvec[tid]; }
        if (tid < 8)   gred[tid] = 0.f;
    }
    __syncthreads();

    // ---------------- phase 1: in_proj (thread = (p=wave, d=lane)) ----------------
    const int p = tid >> 6;
    const int d = tid & 63;
    float uacc[8], zacc[8];
#pragma unroll
    for (int t = 0; t < 8; ++t) { uacc[t] = 0.f; zacc[t] = 0.f; }
#pragma unroll
    for (int dd4 = 0; dd4 < 8; ++dd4) {
        const float wu0 = Win_s[d * WINS + dd4 * 4 + 0];
        const float wu1 = Win_s[d * WINS + dd4 * 4 + 1];
        const float wu2 = Win_s[d * WINS + dd4 * 4 + 2];
        const float wu3 = Win_s[d * WINS + dd4 * 4 + 3];
        const float wz0 = Win_s[(64 + d) * WINS + dd4 * 4 + 0];
        const float wz1 = Win_s[(64 + d) * WINS + dd4 * 4 + 1];
        const float wz2 = Win_s[(64 + d) * WINS + dd4 * 4 + 2];
        const float wz3 = Win_s[(64 + d) * WINS + dd4 * 4 + 3];
#pragma unroll
        for (int t = 0; t < 8; ++t) {
            const float4 a4 = *reinterpret_cast<const float4*>(&xf_s[p * XFS + t * 32 + dd4 * 4]);
            uacc[t] = fmaf(a4.x, wu0, fmaf(a4.y, wu1, fmaf(a4.z, wu2, fmaf(a4.w, wu3, uacc[t]))));
            zacc[t] = fmaf(a4.x, wz0, fmaf(a4.y, wz1, fmaf(a4.z, wz2, fmaf(a4.w, wz3, zacc[t]))));
        }
    }

    // ---------------- phase 2: causal depthwise conv (T=8,K=4) + SiLU ----------------
    float u2r[8];
    {
        const float cw0 = convw_s[d * 5 + 0], cw1 = convw_s[d * 5 + 1];
        const float cw2 = convw_s[d * 5 + 2], cw3 = convw_s[d * 5 + 3];
        const float cb = convb_s[d];
#pragma unroll
        for (int t = 0; t < 8; ++t) {
            float acc = fmaf(uacc[t], cw3, cb);
            if (t >= 1) acc = fmaf(uacc[t - 1], cw2, acc);
            if (t >= 2) acc = fmaf(uacc[t - 2], cw1, acc);
            if (t >= 3) acc = fmaf(uacc[t - 3], cw0, acc);
            u2r[t] = acc * sigmoidf_(acc);
            u2_s[(p * 8 + t) * U2S + d] = u2r[t];
        }
    }
    __syncthreads();

    // ---------------- phase 3: x_proj -> dt,B,C (thread = (pt, j0)) ----------------
    {
        const int pt = tid >> 3, j0 = tid & 7;
        const float* u2row = &u2_s[pt * U2S];
        float acc[5] = {0.f, 0.f, 0.f, 0.f, 0.f};
#pragma unroll
        for (int e4 = 0; e4 < 16; ++e4) {
            const float4 a4 = *reinterpret_cast<const float4*>(&u2row[e4 * 4]);
#pragma unroll
            for (int k = 0; k < 5; ++k) {
                const int j = j0 + (k << 3);
                if (j < 34) {
                    const float4 w4 = *reinterpret_cast<const float4*>(&Wxp_s[j * WXPS + e4 * 4]);
                    acc[k] = fmaf(a4.x, w4.x, fmaf(a4.y, w4.y, fmaf(a4.z, w4.z, fmaf(a4.w, w4.w, acc[k]))));
                }
            }
        }
#pragma unroll
        for (int k = 0; k < 5; ++k) {
            const int j = j0 + (k << 3);
            if (j < 34) bc_s[pt * BCS + (j < 2 ? j : j + 2)] = acc[k];
        }
    }
    __syncthreads();

    // ---------------- phase 4: delta + selective scan + gate (thread = (p,d)) ----------------
    {
        float a_d[16];
#pragma unroll
        for (int s = 0; s < 16; ++s) a_d[s] = A_s[d * 17 + s];
        const float w0 = dtw_s[2 * d], w1 = dtw_s[2 * d + 1];
        const float bb = dtb_s[d], dpv = Dp_s[d];
        float h[16];
#pragma unroll
        for (int s = 0; s < 16; ++s) h[s] = 0.f;
#pragma unroll
        for (int t = 0; t < 8; ++t) {
            const float* bcrow = &bc_s[(p * 8 + t) * BCS];
            const float2 dt2 = *reinterpret_cast<const float2*>(&bcrow[0]);
            float dlt = fmaf(dt2.x, w0, fmaf(dt2.y, w1, bb));
            dlt = (dlt > 15.f) ? dlt : log1pf(__expf(dlt));   // softplus
            const float du = dlt * u2r[t];
            float Bv[16], Cv[16];
            *reinterpret_cast<float4*>(&Bv[0])  = *reinterpret_cast<const float4*>(&bcrow[4]);
            *reinterpret_cast<float4*>(&Bv[4])  = *reinterpret_cast<const float4*>(&bcrow[8]);
            *reinterpret_cast<float4*>(&Bv[8])  = *reinterpret_cast<const float4*>(&bcrow[12]);
            *reinterpret_cast<float4*>(&Bv[12]) = *reinterpret_cast<const float4*>(&bcrow[16]);
            *reinterpret_cast<float4*>(&Cv[0])  = *reinterpret_cast<const float4*>(&bcrow[20]);
            *reinterpret_cast<float4*>(&Cv[4])  = *reinterpret_cast<const float4*>(&bcrow[24]);
            *reinterpret_cast<float4*>(&Cv[8])  = *reinterpret_cast<const float4*>(&bcrow[28]);
            *reinterpret_cast<float4*>(&Cv[12]) = *reinterpret_cast<const float4*>(&bcrow[32]);
            float yv = 0.f;
#pragma unroll
            for (int s = 0; s < 16; ++s) {
                const float dA = __expf(dlt * a_d[s]);
                h[s] = fmaf(h[s], dA, du * Bv[s]);
                yv = fmaf(h[s], Cv[s], yv);
            }
            const float zz = zacc[t];
            const float yfin = fmaf(u2r[t], dpv, yv) * (zz * sigmoidf_(zz));
            u2_s[(p * 8 + t) * U2S + d] = yfin;   // own slot: no cross-thread hazard
        }
    }
    __syncthreads();

    // ---------------- phase 6: out_proj + GN partials (thread = (p6,t6,m0)) ----------------
    {
        const int m0 = tid & 7;
        const int t6 = (tid >> 3) & 7;
        const int p6 = tid >> 6;
        const float* yrow = &u2_s[(p6 * 8 + t6) * U2S];
        float acc[4] = {0.f, 0.f, 0.f, 0.f};
#pragma unroll
        for (int e4 = 0; e4 < 16; ++e4) {
            const float4 a4 = *reinterpret_cast<const float4*>(&yrow[e4 * 4]);
#pragma unroll
            for (int k = 0; k < 4; ++k) {
                const float4 w4 = *reinterpret_cast<const float4*>(&Wout_s[(m0 + (k << 3)) * WOUTS + e4 * 4]);
                acc[k] = fmaf(a4.x, w4.x, fmaf(a4.y, w4.y, fmaf(a4.z, w4.z, fmaf(a4.w, w4.w, acc[k]))));
            }
        }
        float s1 = 0.f, s2 = 0.f;
#pragma unroll
        for (int k = 0; k < 4; ++k) {
            const float v = acc[k];
            s1 += v; s2 = fmaf(v, v, s2);
            xf_s[p6 * XFS + ((m0 + (k << 3)) << 3) + t6] = v;   // stage out as [p][m*8+t]
        }
        // lanes [0..15]->g0, [16..31]->g1, ... : group uniform per 16-lane cluster
#pragma unroll
        for (int off = 1; off < 16; off <<= 1) {
            s1 += __shfl_xor(s1, off);
            s2 += __shfl_xor(s2, off);
        }
        if ((tid & 15) == 0) {
            const int g = t6 >> 1;
            atomicAdd(&gred[g * 2], s1);
            atomicAdd(&gred[g * 2 + 1], s2);
        }
    }
    __syncthreads();

    // ---------------- phase 7: coalesced global write + stats flush ----------------
    {
        float* ob = pre + ((b * CHN_) << 12) + hw0;
        const int pp = tid & 15, c0 = tid >> 4;
#pragma unroll
        for (int k = 0; k < 4; ++k) {
            const int c = c0 + (k << 6);                       // chn = t*32+m
            ob[(c << 12) + pp] = xf_s[pp * XFS + ((c & 31) << 3) + (c >> 5)];
        }
        if (tid < 8) atomicAdd(&stats[(b << 3) + tid], gred[tid]);
    }
}

// GroupNorm + SiLU + residual, in-place on d_out
__global__ __launch_bounds__(256) void spe_gn(
    const float* __restrict__ x, float* __restrict__ io,
    const float* __restrict__ gnw, const float* __restrict__ gnb,
    const float* __restrict__ stats)
{
    const int i = blockIdx.x * 256 + threadIdx.x;   // float4 index, 1048576 total
    const int fi = i << 2;
    const int b = fi >> 20;
    const int chn = (fi >> 12) & 255;
    const int g = chn >> 6;
    const float inv = 1.f / 262144.f;
    const float s1 = stats[(b << 3) + (g << 1)];
    const float s2 = stats[(b << 3) + (g << 1) + 1];
    const float mean = s1 * inv;
    const float var = fmaf(-mean, mean, s2 * inv);
    const float rstd = rsqrtf(var + EPS_);
    const float gw = gnw[chn] * rstd;
    const float gb = gnb[chn];
    const float4 pv = reinterpret_cast<const float4*>(io)[i];
    const float4 xv = reinterpret_cast<const float4*>(x)[i];
    float4 r;
    {
        const float xn = fmaf(pv.x - mean, gw, gb); r.x = xv.x + xn * sigmoidf_(xn);
    }
    {
        const float xn = fmaf(pv.y - mean, gw, gb); r.y = xv.y + xn * sigmoidf_(xn);
    }
    {
        const float xn = fmaf(pv.z - mean, gw, gb); r.z = xv.z + xn * sigmoidf_(xn);
    }
    {
        const float xn = fmaf(pv.w - mean, gw, gb); r.w = xv.w + xn * sigmoidf_(xn);
    }
    reinterpret_cast<float4*>(io)[i] = r;
}

extern "C" void kernel_launch(void* const* d_in, const int* in_sizes, int n_in,
                              void* d_out, int out_size, void* d_ws, size_t ws_size,
                              hipStream_t stream) {
    const float* x     = (const float*)d_in[0];
    const float* Win   = (const float*)d_in[1];
    const float* convw = (const float*)d_in[2];
    const float* convb = (const float*)d_in[3];
    const float* Wxp   = (const float*)d_in[4];
    const float* dtwp  = (const float*)d_in[5];
    const float* dtbp  = (const float*)d_in[6];
    const float* Alog  = (const float*)d_in[7];
    const float* Dv    = (const float*)d_in[8];
    const float* Wout  = (const float*)d_in[9];
    const float* gnw   = (const float*)d_in[10];
    const float* gnb   = (const float*)d_in[11];
    float* out   = (float*)d_out;
    float* stats = (float*)d_ws;   // 32 floats

    hipMemsetAsync(stats, 0, 32 * sizeof(float), stream);
    spe_mamba_main<<<1024, 1024, 0, stream>>>(x, Win, convw, convb, Wxp, dtwp, dtbp,
                                              Alog, Dv, Wout, out, stats);
    spe_gn<<<4096, 256, 0, stream>>>(x, out, gnw, gnb, stats);
}